// Round 6
// baseline (3552.478 us; speedup 1.0000x reference)
//
#include <hip/hip_runtime.h>

#define B_ 64
#define S_ 512
#define H_ 512

typedef unsigned short u16;
typedef unsigned int   u32;
typedef unsigned long long u64;

typedef __attribute__((ext_vector_type(8))) short    bf16x8;
typedef __attribute__((ext_vector_type(8))) _Float16 f16x8;
typedef __attribute__((ext_vector_type(4))) float    f32x4;
typedef __attribute__((ext_vector_type(2))) _Float16 h2_t;

#define PJ_GATE ((size_t)512 * 64 * 512)   // P stride per gate: [512 ts][64 b][512 j]

// ---------- helpers ----------
__device__ inline u16 f2bf(float f) {            // RNE fp32 -> bf16 bits
  u32 u = __builtin_bit_cast(u32, f);
  u32 r = (u + 0x7fffu + ((u >> 16) & 1u)) >> 16;
  return (u16)r;
}
__device__ inline u32 pkbf2(float a, float b) {
  return (u32)f2bf(a) | ((u32)f2bf(b) << 16);
}
__device__ inline u16 f2h(float a) {
  _Float16 x = (_Float16)a;
  return __builtin_bit_cast(u16, x);
}
__device__ inline u32 pk2h(float a, float b) {   // pack two f32 -> half2 bits
  return (u32)f2h(a) | ((u32)f2h(b) << 16);
}
__device__ inline float sigmoidf_(float x) { return 1.f / (1.f + __expf(-x)); }
__device__ inline float tanhf_(float x) {
  float e = __expf(-2.f * fabsf(x));
  float t = (1.f - e) / (1.f + e);
  return copysignf(t, x);
}
__device__ inline void xstore64(u64* p, u64 v) {
  __hip_atomic_store(p, v, __ATOMIC_RELAXED, __HIP_MEMORY_SCOPE_AGENT);
}
__device__ inline u64 xload(const u64* p) {
  return __hip_atomic_load(p, __ATOMIC_RELAXED, __HIP_MEMORY_SCOPE_AGENT);
}

// ---------- kernel 1: W recurrent half -> f16 MFMA A-fragments ----------
// WF[g][rt][kt][lane] (uint4) : 8 f16 = W_g[rt*16 + (lane&15)][512 + kt*32 + (lane>>4)*8 + 0..7]
__global__ void k_convert_w(const float* __restrict__ Wr, const float* __restrict__ Wz,
                            const float* __restrict__ Wh, uint4* __restrict__ WF) {
  int g = blockIdx.y;
  const float* Ws = (g == 0) ? Wr : ((g == 1) ? Wz : Wh);
  int i = blockIdx.x * 256 + threadIdx.x;   // 0..32767
  int lane = i & 63;
  int kt   = (i >> 6) & 15;
  int rt   = i >> 10;                       // 0..31
  int row  = rt * 16 + (lane & 15);
  int col  = 512 + kt * 32 + (lane >> 4) * 8;
  const float* src = Ws + (size_t)row * 1024 + col;
  float4 a = *(const float4*)src;
  float4 b = *(const float4*)(src + 4);
  uint4 o;
  o.x = pk2h(a.x, a.y); o.y = pk2h(a.z, a.w);
  o.z = pk2h(b.x, b.y); o.w = pk2h(b.z, b.w);
  WF[((size_t)(g * 32 + rt) * 16 + kt) * 64 + lane] = o;
}

// ---------- kernel 2: projection GEMM (f32 in, bf16 MFMA, f16 out) ----------
// P[g][s][b][j] = f16( sum_k x[b,s,k]*W_g[j,k] + bias_g[j] )
__global__ __launch_bounds__(256) void k_proj_gemm(
    const float* __restrict__ x,      // [B*S][512] f32 (rows m = b*512+s)
    const float* __restrict__ Wr, const float* __restrict__ Wz, const float* __restrict__ Wh,
    const float* __restrict__ br, const float* __restrict__ bz, const float* __restrict__ bh,
    u16* __restrict__ P)
{
  const int g  = blockIdx.z;
  const int bm = blockIdx.x * 64;
  const int bn = blockIdx.y * 64;
  const float* Ws = (g == 0) ? Wr : ((g == 1) ? Wz : Wh);
  __shared__ __align__(16) u16 As[64][32];
  __shared__ __align__(16) u16 Bs[64][32];
  const int tid  = threadIdx.x;
  const int lane = tid & 63;
  const int wm   = (tid >> 6) >> 1;
  const int wn   = (tid >> 6) & 1;
  const int srow = tid >> 2;
  const int scol = (tid & 3) * 8;

  f32x4 zero4 = {0.f, 0.f, 0.f, 0.f};
  f32x4 acc[2][2];
  acc[0][0] = zero4; acc[0][1] = zero4; acc[1][0] = zero4; acc[1][1] = zero4;

  for (int k0 = 0; k0 < 512; k0 += 32) {
    __syncthreads();
    {
      const float* xs = x + (size_t)(bm + srow) * 512 + k0 + scol;
      float4 a = *(const float4*)xs, b = *(const float4*)(xs + 4);
      uint4 av; av.x = pkbf2(a.x, a.y); av.y = pkbf2(a.z, a.w);
      av.z = pkbf2(b.x, b.y); av.w = pkbf2(b.z, b.w);
      *(uint4*)(&As[srow][scol]) = av;
      const float* wsrc = Ws + (size_t)(bn + srow) * 1024 + k0 + scol;   // input half k<512
      float4 c = *(const float4*)wsrc, d = *(const float4*)(wsrc + 4);
      uint4 bv; bv.x = pkbf2(c.x, c.y); bv.y = pkbf2(c.z, c.w);
      bv.z = pkbf2(d.x, d.y); bv.w = pkbf2(d.z, d.w);
      *(uint4*)(&Bs[srow][scol]) = bv;
    }
    __syncthreads();
#pragma unroll
    for (int mi = 0; mi < 2; ++mi) {
      bf16x8 a = *(const bf16x8*)(&As[wm * 32 + mi * 16 + (lane & 15)][(lane >> 4) * 8]);
#pragma unroll
      for (int ni = 0; ni < 2; ++ni) {
        bf16x8 b = *(const bf16x8*)(&Bs[wn * 32 + ni * 16 + (lane & 15)][(lane >> 4) * 8]);
        acc[mi][ni] = __builtin_amdgcn_mfma_f32_16x16x32_bf16(a, b, acc[mi][ni], 0, 0, 0);
      }
    }
  }
  const float* bias = (g == 0) ? br : ((g == 1) ? bz : bh);
#pragma unroll
  for (int mi = 0; mi < 2; ++mi)
#pragma unroll
    for (int ni = 0; ni < 2; ++ni) {
      int col  = bn + wn * 32 + ni * 16 + (lane & 15);
      float bv = bias[col];
#pragma unroll
      for (int r = 0; r < 4; ++r) {
        int row = bm + wm * 32 + mi * 16 + (lane >> 4) * 4 + r;
        int bb = row >> 9, ss = row & 511;
        float v = acc[mi][ni][r] + bv;
        P[((size_t)g * 512 + ss) * (64 * 512) + (size_t)bb * 512 + col] =
            __builtin_bit_cast(u16, (_Float16)v);
      }
    }
}

// ---------- kernel 3: GRU scan — row-split, pinned-VGPR W, batched polls ----------
// 16 blocks x 512 thr. cluster c = blockIdx>>2 owns batches 16c..16c+15;
// block q = blockIdx&3 owns rows [128q,128q+128): W_r,W_z pinned in VGPRs
// (asm "+v" prevents rematerialization), W_h in LDS (128KB).
// Exchange: u32 slots (tag<<16)|f16 in [b][k] layout; writers publish 2xu64;
// readers issue all 6 u64 poll loads before waiting.
__global__ __launch_bounds__(512, 2) void k_gru_scan(
    const float* __restrict__ h0,
    const u16*  __restrict__ P,       // [3][512 ts][64 b][512 j] f16
    const uint4* __restrict__ WF,     // fragment-packed recurrent W (f16)
    u32* __restrict__ RHX,            // [2 par][4 c][16 b][512 k] tagged r*h
    u32* __restrict__ HX,             // [2 par][4 c][16 b][512 j] tagged h
    float* __restrict__ y,
    float* __restrict__ hlast)
{
  const int q = blockIdx.x & 3;
  const int c = blockIdx.x >> 2;
  const int t = threadIdx.x;
  const int w = t >> 6;          // wave 0..7
  const int l = t & 63;
  const int bq = l & 15;         // batch within cluster
  const int g4 = l >> 4;         // 0..3
  const int bglob = c * 16 + bq;
  const int rt  = q * 8 + w;
  const int j0A = q * 128 + w * 16 + g4 * 4;   // own rows (4)

  __shared__ __align__(16) u16 whlds[8 * 16 * 512];  // 128 KB [w][kt][lane*8]
  __shared__ __align__(16) u16 hbuf[16 * 520];       // f16, reused h -> rh -> h

  // --- W_r/W_z fragments into VGPRs (pinned); W_h into LDS ---
  f16x8 wr[16], wz[16];
#pragma unroll
  for (int kt = 0; kt < 16; ++kt) {
    wr[kt] = __builtin_bit_cast(f16x8, WF[((size_t)(0 * 32 + rt) * 16 + kt) * 64 + l]);
    wz[kt] = __builtin_bit_cast(f16x8, WF[((size_t)(1 * 32 + rt) * 16 + kt) * 64 + l]);
    *(uint4*)&whlds[((w * 16 + kt) * 64 + l) * 8] =
        WF[((size_t)(2 * 32 + rt) * 16 + kt) * 64 + l];
  }
#pragma unroll
  for (int kt = 0; kt < 16; ++kt)
    asm volatile("" : "+v"(wr[kt]), "+v"(wz[kt]));   // pin: no remat, no reload

  // --- init h ---
  f32x4 hold = *(const f32x4*)(h0 + (size_t)bglob * 512 + j0A);
  {
    int b = t >> 5, j = (t & 31) * 16;
    const float4* s = (const float4*)(h0 + (size_t)(c * 16 + b) * 512 + j);
    float4 v0 = s[0], v1 = s[1], v2 = s[2], v3 = s[3];
    uint4 o0, o1;
    o0.x = pk2h(v0.x, v0.y); o0.y = pk2h(v0.z, v0.w);
    o0.z = pk2h(v1.x, v1.y); o0.w = pk2h(v1.z, v1.w);
    o1.x = pk2h(v2.x, v2.y); o1.y = pk2h(v2.z, v2.w);
    o1.z = pk2h(v3.x, v3.y); o1.w = pk2h(v3.z, v3.w);
    uint4* d = (uint4*)&hbuf[b * 520 + j];
    d[0] = o0; d[1] = o1;
  }
  __syncthreads();

  const u16* Ppr = P + (size_t)bglob * 512 + j0A;
  const u16* Ppz = P + PJ_GATE + (size_t)bglob * 512 + j0A;
  const u16* Pph = P + 2 * PJ_GATE + (size_t)bglob * 512 + j0A;

  // poll-reader mapping: b = t>>5 (0..15), k = quarter*128 + (t&31)*4
  const int bR = t >> 5;
  const int kR = (t & 31) * 4;
  const int k1 = ((q + 1) & 3) * 128 + kR;
  const int k2 = ((q + 2) & 3) * 128 + kR;
  const int k3 = ((q + 3) & 3) * 128 + kR;
  const int CL  = 16 * 512;                // u32 per cluster
  const int PAR = 4 * CL;                  // u32 per parity

  uint2 pru = *(const uint2*)Ppr;
  uint2 pzu = *(const uint2*)Ppz;

#define POLL_INTO_HBUF(Xp)                                                      \
  {                                                                             \
    const u64* p1 = (const u64*)((Xp) + bR * 512 + k1);                         \
    const u64* p2 = (const u64*)((Xp) + bR * 512 + k2);                         \
    const u64* p3 = (const u64*)((Xp) + bR * 512 + k3);                         \
    u64 A1 = xload(p1), B1 = xload(p1 + 1);                                     \
    u64 A2 = xload(p2), B2 = xload(p2 + 1);                                     \
    u64 A3 = xload(p3), B3 = xload(p3 + 1);                                     \
    while (((A1 ^ tp) & TMASK) != 0ull) { __builtin_amdgcn_s_sleep(1); A1 = xload(p1); } \
    while (((B1 ^ tp) & TMASK) != 0ull) { __builtin_amdgcn_s_sleep(1); B1 = xload(p1 + 1); } \
    while (((A2 ^ tp) & TMASK) != 0ull) { __builtin_amdgcn_s_sleep(1); A2 = xload(p2); } \
    while (((B2 ^ tp) & TMASK) != 0ull) { __builtin_amdgcn_s_sleep(1); B2 = xload(p2 + 1); } \
    while (((A3 ^ tp) & TMASK) != 0ull) { __builtin_amdgcn_s_sleep(1); A3 = xload(p3); } \
    while (((B3 ^ tp) & TMASK) != 0ull) { __builtin_amdgcn_s_sleep(1); B3 = xload(p3 + 1); } \
    uint2 w1, w2, w3;                                                           \
    w1.x = (u32)(A1 & 0xffffu) | (((u32)(A1 >> 32) & 0xffffu) << 16);           \
    w1.y = (u32)(B1 & 0xffffu) | (((u32)(B1 >> 32) & 0xffffu) << 16);           \
    w2.x = (u32)(A2 & 0xffffu) | (((u32)(A2 >> 32) & 0xffffu) << 16);           \
    w2.y = (u32)(B2 & 0xffffu) | (((u32)(B2 >> 32) & 0xffffu) << 16);           \
    w3.x = (u32)(A3 & 0xffffu) | (((u32)(A3 >> 32) & 0xffffu) << 16);           \
    w3.y = (u32)(B3 & 0xffffu) | (((u32)(B3 >> 32) & 0xffffu) << 16);           \
    *(uint2*)&hbuf[bR * 520 + k1] = w1;                                         \
    *(uint2*)&hbuf[bR * 520 + k2] = w2;                                         \
    *(uint2*)&hbuf[bR * 520 + k3] = w3;                                         \
  }

  const u64 TMASK = 0xffff0000ffff0000ull;

  for (int ts = 0; ts < S_; ++ts) {
    const int par = ts & 1;
    const u32 tag = (u32)(ts + 1);
    const u64 tp  = ((u64)tag << 16) | ((u64)tag << 48);
    u32* RHXp = RHX + par * PAR + c * CL;
    u32* HXp  = HX  + par * PAR + c * CL;

    // prefetch P_h for this step (used in phase B)
    uint2 phu = *(const uint2*)(Pph + (size_t)ts * 32768);

    // ---- phase A: r,z = sigmoid(W_rz · h + P_rz), own 128 rows ----
    f32x4 ar = {0.f, 0.f, 0.f, 0.f}, az = {0.f, 0.f, 0.f, 0.f};
#pragma unroll
    for (int kt = 0; kt < 16; ++kt) {
      f16x8 hv = *(const f16x8*)&hbuf[bq * 520 + g4 * 8 + kt * 32];
      ar = __builtin_amdgcn_mfma_f32_16x16x32_f16(wr[kt], hv, ar, 0, 0, 0);
      az = __builtin_amdgcn_mfma_f32_16x16x32_f16(wz[kt], hv, az, 0, 0, 0);
    }
    h2_t pr0 = __builtin_bit_cast(h2_t, pru.x), pr1 = __builtin_bit_cast(h2_t, pru.y);
    h2_t pz0 = __builtin_bit_cast(h2_t, pzu.x), pz1 = __builtin_bit_cast(h2_t, pzu.y);
    float rr0 = sigmoidf_(ar[0] + (float)pr0[0]);
    float rr1 = sigmoidf_(ar[1] + (float)pr0[1]);
    float rr2 = sigmoidf_(ar[2] + (float)pr1[0]);
    float rr3 = sigmoidf_(ar[3] + (float)pr1[1]);
    float zz0 = sigmoidf_(az[0] + (float)pz0[0]);
    float zz1 = sigmoidf_(az[1] + (float)pz0[1]);
    float zz2 = sigmoidf_(az[2] + (float)pz1[0]);
    float zz3 = sigmoidf_(az[3] + (float)pz1[1]);
    u16 rh0 = f2h(rr0 * hold[0]), rh1 = f2h(rr1 * hold[1]);
    u16 rh2 = f2h(rr2 * hold[2]), rh3 = f2h(rr3 * hold[3]);
    // publish own rh (tagged u64 x2, [b][k] layout)
    {
      u64 v01 = (u64)((tag << 16) | rh0) | ((u64)((tag << 16) | rh1) << 32);
      u64 v23 = (u64)((tag << 16) | rh2) | ((u64)((tag << 16) | rh3) << 32);
      xstore64((u64*)(RHXp + bq * 512 + j0A), v01);
      xstore64((u64*)(RHXp + bq * 512 + j0A + 2), v23);
    }
    __syncthreads();   // everyone done reading h from hbuf
    // own rh -> hbuf; poll remote rh -> hbuf
    *(uint2*)&hbuf[bq * 520 + j0A] =
        uint2{(u32)rh0 | ((u32)rh1 << 16), (u32)rh2 | ((u32)rh3 << 16)};
    POLL_INTO_HBUF(RHXp)
    __syncthreads();   // rh complete in hbuf

    // ---- phase B: htilde own rows; update h ----
    f32x4 ah = {0.f, 0.f, 0.f, 0.f};
#pragma unroll
    for (int kt = 0; kt < 16; ++kt) {
      f16x8 rv = *(const f16x8*)&hbuf[bq * 520 + g4 * 8 + kt * 32];
      f16x8 wh = *(const f16x8*)&whlds[((w * 16 + kt) * 64 + l) * 8];
      ah = __builtin_amdgcn_mfma_f32_16x16x32_f16(wh, rv, ah, 0, 0, 0);
    }
    h2_t ph0 = __builtin_bit_cast(h2_t, phu.x), ph1 = __builtin_bit_cast(h2_t, phu.y);
    float ht0 = tanhf_(ah[0] + (float)ph0[0]);
    float ht1 = tanhf_(ah[1] + (float)ph0[1]);
    float ht2 = tanhf_(ah[2] + (float)ph1[0]);
    float ht3 = tanhf_(ah[3] + (float)ph1[1]);
    f32x4 hn;
    hn[0] = zz0 * ht0 + (1.f - zz0) * hold[0];
    hn[1] = zz1 * ht1 + (1.f - zz1) * hold[1];
    hn[2] = zz2 * ht2 + (1.f - zz2) * hold[2];
    hn[3] = zz3 * ht3 + (1.f - zz3) * hold[3];
    hold = hn;
    __builtin_nontemporal_store(hn,
        (f32x4*)(y + (size_t)bglob * 262144 + (size_t)ts * 512 + j0A));
    u16 h0b = f2h(hn[0]), h1b = f2h(hn[1]), h2b = f2h(hn[2]), h3b = f2h(hn[3]);
    {
      u64 v01 = (u64)((tag << 16) | h0b) | ((u64)((tag << 16) | h1b) << 32);
      u64 v23 = (u64)((tag << 16) | h2b) | ((u64)((tag << 16) | h3b) << 32);
      xstore64((u64*)(HXp + bq * 512 + j0A), v01);
      xstore64((u64*)(HXp + bq * 512 + j0A + 2), v23);
    }

    // prefetch next step's P_r/P_z while publish propagates
    {
      int tsn = (ts < S_ - 1) ? ts + 1 : ts;
      pru = *(const uint2*)(Ppr + (size_t)tsn * 32768);
      pzu = *(const uint2*)(Ppz + (size_t)tsn * 32768);
    }

    __syncthreads();   // everyone done reading rh from hbuf
    *(uint2*)&hbuf[bq * 520 + j0A] =
        uint2{(u32)h0b | ((u32)h1b << 16), (u32)h2b | ((u32)h3b << 16)};
    POLL_INTO_HBUF(HXp)
    __syncthreads();   // h complete in hbuf
  }

  *(f32x4*)(hlast + (size_t)bglob * 512 + j0A) = hold;
}

// ---------- host ----------
extern "C" void kernel_launch(void* const* d_in, const int* in_sizes, int n_in,
                              void* d_out, int out_size, void* d_ws, size_t ws_size,
                              hipStream_t stream) {
  const float* x  = (const float*)d_in[0];
  const float* h0 = (const float*)d_in[1];
  const float* Wr = (const float*)d_in[2];
  const float* br = (const float*)d_in[3];
  const float* Wz = (const float*)d_in[4];
  const float* bz = (const float*)d_in[5];
  const float* Wh = (const float*)d_in[6];
  const float* bh = (const float*)d_in[7];

  char* ws = (char*)d_ws;
  // layout: WF 1.5MB @0 | P 96MB @2MB | RHX 256KB | HX 256KB
  uint4* WF  = (uint4*)ws;
  u16*   P   = (u16*)(ws + 2097152);
  u32*   RHX = (u32*)(ws + 102760448);
  u32*   HX  = (u32*)(ws + 103022592);

  float* y     = (float*)d_out;
  float* hlast = y + (size_t)B_ * S_ * H_;

  hipMemsetAsync(ws + 102760448, 0, 524288, stream);   // clear exchange tags
  k_convert_w<<<dim3(128, 3), dim3(256), 0, stream>>>(Wr, Wz, Wh, WF);
  k_proj_gemm<<<dim3(512, 8, 3), dim3(256), 0, stream>>>(x, Wr, Wz, Wh, br, bz, bh, P);
  k_gru_scan<<<dim3(16), dim3(512), 0, stream>>>(h0, P, WF, RHX, HX, y, hlast);
}